// Round 1
// baseline (1415.431 us; speedup 1.0000x reference)
//
#include <hip/hip_runtime.h>

#define NTRAIN 32768
#define NTEST  4096
#define DIM    64
#define KSEL   32
#define NHALF  16384   // train points per selection half
#define NLAB   1000

// monotone float -> uint mapping (preserves total order incl. negatives)
__device__ __forceinline__ unsigned f2u(float f){
  unsigned b = __float_as_uint(f);
  return (b & 0x80000000u) ? ~b : (b | 0x80000000u);
}

// Pre-transpose x_train into tiles xT[j/256][d][256] and compute b2[j] = ||x_train[j]||^2
__global__ void prep_kernel(const float* __restrict__ xtr,
                            float* __restrict__ xT, float* __restrict__ b2){
  int j  = blockIdx.x * 256 + threadIdx.x;
  int ib = j >> 8, c = j & 255;
  const float* row = xtr + (size_t)j * DIM;
  float s = 0.f;
#pragma unroll
  for (int d = 0; d < DIM; ++d){
    float v = row[d];
    s = fmaf(v, v, s);
    xT[(size_t)ib * (DIM*256) + d*256 + c] = v;
  }
  b2[j] = s;
}

__global__ __launch_bounds__(256) void knn_kernel(
    const float* __restrict__ xT, const float* __restrict__ b2,
    const float* __restrict__ x_train, const float* __restrict__ x_test,
    const int* __restrict__ y_train, const float* __restrict__ w_train,
    int* __restrict__ out)
{
  __shared__ unsigned keys[NHALF];   // 64 KB
  __shared__ unsigned hist[2048];    // 8 KB (reused as votes later)
  __shared__ unsigned psum[256];
  __shared__ unsigned candU[64];
  __shared__ unsigned candI[64];
  __shared__ unsigned tieI[256];
  __shared__ int nCand, nTie;
  __shared__ unsigned sB, sLess;
  __shared__ unsigned sUstar; __shared__ int sNeed;
  __shared__ float rv[256]; __shared__ int rl[256];

  float* votes = (float*)hist;  // overlay: histograms done before voting

  const int t = threadIdx.x;
  const int m = blockIdx.x;

  // test vector (uniform across block -> scalarized by compiler)
  float a[DIM];
  const float* am = x_test + (size_t)m * DIM;
#pragma unroll
  for (int d = 0; d < DIM; ++d) a[d] = am[d];

  if (t == 0) nCand = 0;

  for (int h = 0; h < 2; ++h){
    __syncthreads();   // protect keys[] reuse + nCand init

    // ---- compute sortable keys for this half ----
    if (xT){
      for (int i = 0; i < 64; i += 2){
        const float* p0 = xT + (size_t)(h*64 + i) * (DIM*256) + t;
        const float* p1 = p0 + DIM*256;
        float s00=0.f, s01=0.f, s10=0.f, s11=0.f;
#pragma unroll
        for (int d = 0; d < DIM; d += 2){
          s00 = fmaf(a[d],   p0[ d   *256], s00);
          s01 = fmaf(a[d+1], p0[(d+1)*256], s01);
          s10 = fmaf(a[d],   p1[ d   *256], s10);
          s11 = fmaf(a[d+1], p1[(d+1)*256], s11);
        }
        int j0 = h*NHALF + i*256 + t;
        float k0 = fmaf(-2.f, s00 + s01, b2[j0]);
        float k1 = fmaf(-2.f, s10 + s11, b2[j0 + 256]);
        keys[ i   *256 + t] = f2u(k0);
        keys[(i+1)*256 + t] = f2u(k1);
      }
    } else {
      // fallback: direct squared distance from row-major x_train
      for (int i = 0; i < 64; ++i){
        int j = h*NHALF + i*256 + t;
        const float4* bp = (const float4*)(x_train + (size_t)j * DIM);
        float s = 0.f;
#pragma unroll
        for (int q = 0; q < 16; ++q){
          float4 v = bp[q];
          float e0 = a[4*q]   - v.x, e1 = a[4*q+1] - v.y;
          float e2 = a[4*q+2] - v.z, e3 = a[4*q+3] - v.w;
          s = fmaf(e0,e0,s); s = fmaf(e1,e1,s); s = fmaf(e2,e2,s); s = fmaf(e3,e3,s);
        }
        keys[i*256 + t] = f2u(s);
      }
    }
    __syncthreads();

    // ---- 3-level radix select: exact value of the rank-KSEL key ----
    unsigned target = KSEL;   // rank within current subset
    unsigned pref   = 0;      // matched high-bit prefix
    for (int lev = 0; lev < 3; ++lev){
      const int nb    = (lev == 2) ? 1024 : 2048;
      const int shift = (lev == 0) ? 21 : (lev == 1 ? 10 : 0);
      for (int q = t; q < nb; q += 256) hist[q] = 0;
      __syncthreads();
      for (int i = 0; i < 64; ++i){
        unsigned u = keys[i*256 + t];
        bool ok = (lev == 0) ? true
                : (lev == 1) ? ((u >> 21) == pref)
                             : ((u >> 10) == pref);
        if (ok) atomicAdd(&hist[(u >> shift) & (unsigned)(nb - 1)], 1u);
      }
      __syncthreads();
      // group partial sums + inclusive scan to find crossing group
      const int g = nb / 256;
      unsigned sloc = 0;
      for (int k = 0; k < g; ++k) sloc += hist[t*g + k];
      psum[t] = sloc;
      __syncthreads();
      for (int ofs = 1; ofs < 256; ofs <<= 1){
        unsigned v = (t >= ofs) ? psum[t - ofs] : 0u;
        __syncthreads();
        psum[t] += v;
        __syncthreads();
      }
      unsigned excl = (t == 0) ? 0u : psum[t-1];
      if (excl < target && target <= psum[t]){
        unsigned cum = excl; int b = t*g;
        while (cum + hist[b] < target){ cum += hist[b]; ++b; }
        sB = (unsigned)b; sLess = cum;
      }
      __syncthreads();
      unsigned B = sB, cl = sLess;   // uniform
      target -= cl;
      if      (lev == 0) pref = B;
      else if (lev == 1) pref = (pref << 11) | B;
      else if (t == 0){ sUstar = (pref << 10) | B; sNeed = (int)target; }
    }
    __syncthreads();
    unsigned ustar = sUstar; int need = sNeed;
    if (t == 0) nTie = 0;
    __syncthreads();

    // ---- collect definite (< ustar) and ties (== ustar) ----
    for (int i = 0; i < 64; ++i){
      unsigned u   = keys[i*256 + t];
      unsigned idx = (unsigned)(h*NHALF + i*256 + t);
      if (u < ustar){
        int p = atomicAdd(&nCand, 1);
        if (p < 64){ candU[p] = u; candI[p] = idx; }
      } else if (u == ustar){
        int p = atomicAdd(&nTie, 1);
        if (p < 256) tieI[p] = idx;
      }
    }
    __syncthreads();
    int nT = nTie; if (nT > 256) nT = 256;
    if (t < nT){
      unsigned my = tieI[t]; int r = 0;
      for (int k = 0; k < nT; ++k) r += (tieI[k] < my) ? 1 : 0;
      if (r < need){
        int p = atomicAdd(&nCand, 1);
        if (p < 64){ candU[p] = ustar; candI[p] = my; }
      }
    }
    __syncthreads();
  } // halves

  // ---- final exact top-32 among 64 candidates, then weighted vote ----
  for (int q = t; q < NLAB; q += 256) votes[q] = 0.f;
  __syncthreads();
  int nC = nCand; if (nC > 64) nC = 64;
  if (t < nC){
    unsigned mu = candU[t], mi = candI[t];
    int r = 0;
    for (int k = 0; k < nC; ++k){
      unsigned ku = candU[k], ki = candI[k];
      r += (ku < mu || (ku == mu && ki < mi)) ? 1 : 0;
    }
    if (r < KSEL){
      int lab = y_train[mi];
      atomicAdd(&votes[lab], w_train[mi]);
    }
  }
  __syncthreads();

  // ---- argmax over 1000 labels, lowest label wins ties ----
  float bv = -1.f; int bl = 0;
  for (int l = t; l < NLAB; l += 256){
    float v = votes[l];
    if (v > bv){ bv = v; bl = l; }   // ascending l -> '>' keeps lowest on tie
  }
  rv[t] = bv; rl[t] = bl;
  __syncthreads();
  for (int s = 128; s > 0; s >>= 1){
    if (t < s){
      if (rv[t+s] > rv[t] || (rv[t+s] == rv[t] && rl[t+s] < rl[t])){
        rv[t] = rv[t+s]; rl[t] = rl[t+s];
      }
    }
    __syncthreads();
  }
  if (t == 0) out[m] = rl[0];
}

extern "C" void kernel_launch(void* const* d_in, const int* in_sizes, int n_in,
                              void* d_out, int out_size, void* d_ws, size_t ws_size,
                              hipStream_t stream)
{
  (void)in_sizes; (void)n_in; (void)out_size;
  const float* x_train = (const float*)d_in[0];
  const int*   y_train = (const int*)  d_in[1];
  const float* x_test  = (const float*)d_in[2];
  const float* w_train = (const float*)d_in[3];
  int* out = (int*)d_out;

  const size_t needWS = (size_t)NTRAIN*DIM*sizeof(float) + (size_t)NTRAIN*sizeof(float);
  const bool useT = (ws_size >= needWS);
  float* xT = (float*)d_ws;
  float* b2 = xT + (size_t)NTRAIN*DIM;

  if (useT) prep_kernel<<<NTRAIN/256, 256, 0, stream>>>(x_train, xT, b2);
  knn_kernel<<<NTEST, 256, 0, stream>>>(useT ? xT : nullptr, useT ? b2 : nullptr,
                                        x_train, x_test, y_train, w_train, out);
}

// Round 2
// 544.451 us; speedup vs baseline: 2.5997x; 2.5997x over previous
//
#include <hip/hip_runtime.h>

#define NTRAIN 32768
#define NTEST  4096
#define DIM    64
#define KSEL   32
#define NLAB   1000

#define SAMPLE 1024
#define SRANK  8
#define CAP    1024
#define TB     16
#define SUBN   1024
#define CHUNK  2048
#define NCHUNK (NTRAIN/CHUNK)
#define DS     8
#define POOLCAP 1600

// monotone float -> uint mapping (preserves total order incl. negatives)
__device__ __forceinline__ unsigned f2u(float f){
  unsigned b = __float_as_uint(f);
  return (b & 0x80000000u) ? ~b : (b | 0x80000000u);
}

struct SelScratch {
  unsigned hist[2048];
  unsigned psum[256];
  unsigned sB, sLess, sU;
  int sNeed;
};

// exact value of the rank-th smallest key (1-based) among keys[0..n). n>=rank.
__device__ unsigned radix_select(const unsigned* keys, int n, unsigned rank,
                                 SelScratch* s, int t, int* needOut)
{
  unsigned target = rank, pref = 0;
  for (int lev = 0; lev < 3; ++lev){
    const int nb    = (lev == 2) ? 1024 : 2048;
    const int shift = (lev == 0) ? 21 : (lev == 1 ? 10 : 0);
    for (int q = t; q < nb; q += 256) s->hist[q] = 0;
    __syncthreads();
    for (int i = t; i < n; i += 256){
      unsigned u = keys[i];
      bool ok = (lev == 0) ? true
              : (lev == 1) ? ((u >> 21) == pref)
                           : ((u >> 10) == pref);
      if (ok) atomicAdd(&s->hist[(u >> shift) & (unsigned)(nb - 1)], 1u);
    }
    __syncthreads();
    const int g = nb / 256;
    unsigned sl = 0;
    for (int k = 0; k < g; ++k) sl += s->hist[t*g + k];
    s->psum[t] = sl;
    __syncthreads();
    for (int ofs = 1; ofs < 256; ofs <<= 1){
      unsigned v = (t >= ofs) ? s->psum[t - ofs] : 0u;
      __syncthreads();
      s->psum[t] += v;
      __syncthreads();
    }
    unsigned excl = (t == 0) ? 0u : s->psum[t-1];
    if (excl < target && target <= s->psum[t]){
      unsigned cum = excl; int b = t*g;
      while (cum + s->hist[b] < target){ cum += s->hist[b]; ++b; }
      s->sB = (unsigned)b; s->sLess = cum;
    }
    __syncthreads();
    unsigned B = s->sB, cl = s->sLess;
    target -= cl;
    if      (lev == 0) pref = B;
    else if (lev == 1) pref = (pref << 11) | B;
    else if (t == 0){ s->sU = (pref << 10) | B; s->sNeed = (int)target; }
  }
  __syncthreads();
  *needOut = s->sNeed;
  return s->sU;
}

// exact top-KSEL among (ku,ki)[0..n) by (key asc, idx asc). n>=KSEL. writes selI.
__device__ void select32(const unsigned* ku, const unsigned* ki, int n,
                         SelScratch* s, unsigned* tieI, unsigned* selI,
                         int* selCnt, int* tieCnt, int t)
{
  int need;
  unsigned ustar = radix_select(ku, n, KSEL, s, t, &need);
  if (t == 0){ *selCnt = 0; *tieCnt = 0; }
  __syncthreads();
  for (int i = t; i < n; i += 256){
    unsigned u = ku[i];
    if (u < ustar){ int p = atomicAdd(selCnt, 1); if (p < 40) selI[p] = ki[i]; }
    else if (u == ustar){ int p = atomicAdd(tieCnt, 1); if (p < 256) tieI[p] = ki[i]; }
  }
  __syncthreads();
  int nT = *tieCnt; if (nT > 256) nT = 256;
  if (t < nT){
    unsigned my = tieI[t]; int r = 0;
    for (int k = 0; k < nT; ++k) r += (tieI[k] < my) ? 1 : 0;
    if (r < need){ int p = atomicAdd(selCnt, 1); if (p < 40) selI[p] = my; }
  }
  __syncthreads();
}

// ---- prep: xT[d][j] column-major transpose + b2 ----
__global__ __launch_bounds__(256) void prep(const float* __restrict__ xtr,
                                            float* __restrict__ xT,
                                            float* __restrict__ b2)
{
  int j = blockIdx.x*256 + threadIdx.x;
  const float4* rp = (const float4*)(xtr + (size_t)j * DIM);
  float v[DIM]; float s = 0.f;
#pragma unroll
  for (int q = 0; q < 16; ++q){
    float4 w = rp[q];
    v[4*q]=w.x; v[4*q+1]=w.y; v[4*q+2]=w.z; v[4*q+3]=w.w;
    s = fmaf(w.x,w.x,s); s = fmaf(w.y,w.y,s); s = fmaf(w.z,w.z,s); s = fmaf(w.w,w.w,s);
  }
#pragma unroll
  for (int d = 0; d < DIM; ++d) xT[(size_t)d*NTRAIN + j] = v[d];
  b2[j] = s;
}

// ---- pre-pass: per-test threshold = SRANK-th smallest key over SAMPLE points ----
__global__ __launch_bounds__(256) void pre_kernel(const float* __restrict__ xT,
        const float* __restrict__ b2, const float* __restrict__ x_test,
        unsigned* __restrict__ Tu)
{
  __shared__ unsigned keys[SAMPLE];
  __shared__ SelScratch ss;
  int t = threadIdx.x, m = blockIdx.x;
  float a[DIM];
  const float* am = x_test + (size_t)m * DIM;
#pragma unroll
  for (int d = 0; d < DIM; ++d) a[d] = am[d];
  for (int q = 0; q < SAMPLE/256; ++q){
    int j = q*256 + t;
    float s = 0.f;
#pragma unroll
    for (int d = 0; d < DIM; ++d) s = fmaf(a[d], xT[(size_t)d*NTRAIN + j], s);
    keys[j] = f2u(fmaf(-2.f, s, b2[j]));
  }
  __syncthreads();
  int need;
  unsigned ustar = radix_select(keys, SAMPLE, SRANK, &ss, t, &need);
  if (t == 0) Tu[m] = ustar;
}

// ---- kernel A: register-tiled key GEMM + threshold filter ----
__global__ __launch_bounds__(256) void knnA(const float* __restrict__ xT,
        const float* __restrict__ b2, const float* __restrict__ x_test,
        const unsigned* __restrict__ Tu, unsigned* __restrict__ cnt,
        unsigned* __restrict__ cand)
{
  __shared__ float Bs[DS][SUBN];   // 32KB
  __shared__ float As[DIM][TB];    // 4KB
  __shared__ unsigned Ts[TB];

  const int t = threadIdx.x;
  const int m0 = blockIdx.x * TB;
  const int c0 = blockIdx.y * CHUNK;
  const int rg = t >> 7;        // 0..1 (8 rows each)
  const int cg = t & 127;       // 0..127 (4+4 cols)
  const int wid = t >> 6, lane = t & 63;

  for (int i = t; i < TB*DIM; i += 256){
    int r = i >> 6, d = i & 63;
    As[d][r] = x_test[(size_t)(m0 + r)*DIM + d];
  }
  if (t < TB) Ts[t] = Tu[m0 + t];

  for (int sub = 0; sub < CHUNK/SUBN; ++sub){
    const int j0 = c0 + sub*SUBN;
    float acc[8][8];
#pragma unroll
    for (int r=0;r<8;++r)
#pragma unroll
      for (int c=0;c<8;++c) acc[r][c] = 0.f;

    for (int ds = 0; ds < DIM; ds += DS){
      __syncthreads();   // Bs reuse + (first iter) As/Ts visibility
#pragma unroll
      for (int dd = 0; dd < DS; ++dd){
        const float* src = xT + (size_t)(ds+dd)*NTRAIN + j0 + wid*256 + lane*4;
        __builtin_amdgcn_global_load_lds(
            (const __attribute__((address_space(1))) void*)src,
            (__attribute__((address_space(3))) void*)&Bs[dd][wid*256],
            16, 0, 0);
      }
      __syncthreads();   // compiler drains vmcnt before barrier
#pragma unroll
      for (int dd = 0; dd < DS; ++dd){
        float4 a0 = *(const float4*)&As[ds+dd][rg*8];
        float4 a1 = *(const float4*)&As[ds+dd][rg*8+4];
        float4 b0 = *(const float4*)&Bs[dd][cg*4];
        float4 b1 = *(const float4*)&Bs[dd][512 + cg*4];
        float av[8] = {a0.x,a0.y,a0.z,a0.w,a1.x,a1.y,a1.z,a1.w};
        float bv[8] = {b0.x,b0.y,b0.z,b0.w,b1.x,b1.y,b1.z,b1.w};
#pragma unroll
        for (int r=0;r<8;++r)
#pragma unroll
          for (int c=0;c<8;++c)
            acc[r][c] = fmaf(av[r], bv[c], acc[r][c]);
      }
    }
    // epilogue: key = b2 - 2*dot; append candidates below threshold
    float4 q0 = *(const float4*)&b2[j0 + cg*4];
    float4 q1 = *(const float4*)&b2[j0 + 512 + cg*4];
    float b2v[8] = {q0.x,q0.y,q0.z,q0.w,q1.x,q1.y,q1.z,q1.w};
#pragma unroll
    for (int r=0;r<8;++r){
      int mrow = m0 + rg*8 + r;
      unsigned thr = Ts[rg*8 + r];
#pragma unroll
      for (int c=0;c<8;++c){
        int j = j0 + ((c<4) ? (cg*4 + c) : (512 + cg*4 + (c-4)));
        unsigned u = f2u(fmaf(-2.f, acc[r][c], b2v[c]));
        if (u < thr){
          unsigned p = atomicAdd(&cnt[mrow], 1u);
          if (p < CAP) cand[(size_t)mrow*CAP + p] = (unsigned)j;
        }
      }
    }
  }
}

// ---- kernel B: exact top-32 among candidates (or full-scan fallback), vote, argmax ----
__global__ __launch_bounds__(256) void knnB(const float* __restrict__ x_train,
        const float* __restrict__ xT, const float* __restrict__ b2,
        const float* __restrict__ x_test, const int* __restrict__ y_train,
        const float* __restrict__ w_train, const unsigned* __restrict__ cnt,
        const unsigned* __restrict__ cand, int* __restrict__ out)
{
  __shared__ unsigned ku[POOLCAP], ki[POOLCAP];
  __shared__ unsigned chunkKeys[1024];
  __shared__ SelScratch ss;
  __shared__ unsigned tieI[256];
  __shared__ unsigned selI[40];
  __shared__ int selCnt, tieCnt, poolCnt;
  __shared__ float votes[NLAB];

  const int t = threadIdx.x, m = blockIdx.x;
  float a[DIM];
  const float* am = x_test + (size_t)m*DIM;
#pragma unroll
  for (int d = 0; d < DIM; ++d) a[d] = am[d];

  unsigned c = cnt[m];
  if (c >= KSEL && c <= CAP){
    // main path: recompute exact keys for candidates
    for (int i = t; i < (int)c; i += 256){
      unsigned j = cand[(size_t)m*CAP + i];
      const float4* rp = (const float4*)(x_train + (size_t)j*DIM);
      float s = 0.f;
#pragma unroll
      for (int q = 0; q < 16; ++q){
        float4 w = rp[q];
        s = fmaf(a[4*q],w.x,s); s = fmaf(a[4*q+1],w.y,s);
        s = fmaf(a[4*q+2],w.z,s); s = fmaf(a[4*q+3],w.w,s);
      }
      ku[i] = f2u(fmaf(-2.f, s, b2[j]));
      ki[i] = j;
    }
    __syncthreads();
    select32(ku, ki, (int)c, &ss, tieI, selI, &selCnt, &tieCnt, t);
  } else {
    // fallback (rare): exact full scan in 32 chunks of 1024, pool chunk-top-32s
    if (t == 0) poolCnt = 0;
    __syncthreads();
    for (int ch = 0; ch < NTRAIN/1024; ++ch){
      const int j0 = ch*1024;
      for (int q = 0; q < 4; ++q){
        int jj = q*256 + t;
        float s = 0.f;
#pragma unroll
        for (int d = 0; d < DIM; ++d) s = fmaf(a[d], xT[(size_t)d*NTRAIN + j0 + jj], s);
        chunkKeys[jj] = f2u(fmaf(-2.f, s, b2[j0 + jj]));
      }
      __syncthreads();
      int need;
      unsigned ustar = radix_select(chunkKeys, 1024, KSEL, &ss, t, &need);
      for (int q = 0; q < 4; ++q){
        int jj = q*256 + t;
        unsigned u = chunkKeys[jj];
        if (u <= ustar){
          int p = atomicAdd(&poolCnt, 1);
          if (p < POOLCAP){ ku[p] = u; ki[p] = (unsigned)(j0 + jj); }
        }
      }
      __syncthreads();
    }
    int n = poolCnt; if (n > POOLCAP) n = POOLCAP;
    select32(ku, ki, n, &ss, tieI, selI, &selCnt, &tieCnt, t);
  }

  // weighted vote over 1000 labels
  for (int q = t; q < NLAB; q += 256) votes[q] = 0.f;
  __syncthreads();
  int nSel = selCnt; if (nSel > KSEL) nSel = KSEL;
  if (t < nSel){
    unsigned j = selI[t];
    atomicAdd(&votes[y_train[j]], w_train[j]);
  }
  __syncthreads();

  // argmax, lowest label wins ties
  float* rv = (float*)ss.hist;
  int*   rl = (int*)ss.psum;
  float bv = -1.f; int bl = 0;
  for (int l = t; l < NLAB; l += 256){
    float v = votes[l];
    if (v > bv){ bv = v; bl = l; }
  }
  rv[t] = bv; rl[t] = bl;
  __syncthreads();
  for (int sred = 128; sred > 0; sred >>= 1){
    if (t < sred){
      if (rv[t+sred] > rv[t] || (rv[t+sred] == rv[t] && rl[t+sred] < rl[t])){
        rv[t] = rv[t+sred]; rl[t] = rl[t+sred];
      }
    }
    __syncthreads();
  }
  if (t == 0) out[m] = rl[0];
}

// ---- legacy (round-1, direct-read path): used only if ws too small ----
__global__ __launch_bounds__(256) void knn_legacy(
    const float* __restrict__ x_train, const float* __restrict__ x_test,
    const int* __restrict__ y_train, const float* __restrict__ w_train,
    int* __restrict__ out)
{
  __shared__ unsigned keys[16384];
  __shared__ unsigned hist[2048];
  __shared__ unsigned psum[256];
  __shared__ unsigned candU[64];
  __shared__ unsigned candI[64];
  __shared__ unsigned tieI[256];
  __shared__ int nCand, nTie;
  __shared__ unsigned sB, sLess;
  __shared__ unsigned sUstar; __shared__ int sNeed;
  __shared__ float rv[256]; __shared__ int rl[256];

  float* votes = (float*)hist;
  const int t = threadIdx.x;
  const int m = blockIdx.x;

  float a[DIM];
  const float* am = x_test + (size_t)m * DIM;
#pragma unroll
  for (int d = 0; d < DIM; ++d) a[d] = am[d];

  if (t == 0) nCand = 0;

  for (int h = 0; h < 2; ++h){
    __syncthreads();
    for (int i = 0; i < 64; ++i){
      int j = h*16384 + i*256 + t;
      const float4* bp = (const float4*)(x_train + (size_t)j * DIM);
      float s = 0.f;
#pragma unroll
      for (int q = 0; q < 16; ++q){
        float4 v = bp[q];
        float e0 = a[4*q]   - v.x, e1 = a[4*q+1] - v.y;
        float e2 = a[4*q+2] - v.z, e3 = a[4*q+3] - v.w;
        s = fmaf(e0,e0,s); s = fmaf(e1,e1,s); s = fmaf(e2,e2,s); s = fmaf(e3,e3,s);
      }
      keys[i*256 + t] = f2u(s);
    }
    __syncthreads();

    unsigned target = KSEL;
    unsigned pref   = 0;
    for (int lev = 0; lev < 3; ++lev){
      const int nb    = (lev == 2) ? 1024 : 2048;
      const int shift = (lev == 0) ? 21 : (lev == 1 ? 10 : 0);
      for (int q = t; q < nb; q += 256) hist[q] = 0;
      __syncthreads();
      for (int i = 0; i < 64; ++i){
        unsigned u = keys[i*256 + t];
        bool ok = (lev == 0) ? true
                : (lev == 1) ? ((u >> 21) == pref)
                             : ((u >> 10) == pref);
        if (ok) atomicAdd(&hist[(u >> shift) & (unsigned)(nb - 1)], 1u);
      }
      __syncthreads();
      const int g = nb / 256;
      unsigned sloc = 0;
      for (int k = 0; k < g; ++k) sloc += hist[t*g + k];
      psum[t] = sloc;
      __syncthreads();
      for (int ofs = 1; ofs < 256; ofs <<= 1){
        unsigned v = (t >= ofs) ? psum[t - ofs] : 0u;
        __syncthreads();
        psum[t] += v;
        __syncthreads();
      }
      unsigned excl = (t == 0) ? 0u : psum[t-1];
      if (excl < target && target <= psum[t]){
        unsigned cum = excl; int b = t*g;
        while (cum + hist[b] < target){ cum += hist[b]; ++b; }
        sB = (unsigned)b; sLess = cum;
      }
      __syncthreads();
      unsigned B = sB, cl = sLess;
      target -= cl;
      if      (lev == 0) pref = B;
      else if (lev == 1) pref = (pref << 11) | B;
      else if (t == 0){ sUstar = (pref << 10) | B; sNeed = (int)target; }
    }
    __syncthreads();
    unsigned ustar = sUstar; int need = sNeed;
    if (t == 0) nTie = 0;
    __syncthreads();

    for (int i = 0; i < 64; ++i){
      unsigned u   = keys[i*256 + t];
      unsigned idx = (unsigned)(h*16384 + i*256 + t);
      if (u < ustar){
        int p = atomicAdd(&nCand, 1);
        if (p < 64){ candU[p] = u; candI[p] = idx; }
      } else if (u == ustar){
        int p = atomicAdd(&nTie, 1);
        if (p < 256) tieI[p] = idx;
      }
    }
    __syncthreads();
    int nT = nTie; if (nT > 256) nT = 256;
    if (t < nT){
      unsigned my = tieI[t]; int r = 0;
      for (int k = 0; k < nT; ++k) r += (tieI[k] < my) ? 1 : 0;
      if (r < need){
        int p = atomicAdd(&nCand, 1);
        if (p < 64){ candU[p] = ustar; candI[p] = my; }
      }
    }
    __syncthreads();
  }

  for (int q = t; q < NLAB; q += 256) votes[q] = 0.f;
  __syncthreads();
  int nC = nCand; if (nC > 64) nC = 64;
  if (t < nC){
    unsigned mu = candU[t], mi = candI[t];
    int r = 0;
    for (int k = 0; k < nC; ++k){
      unsigned kku = candU[k], kki = candI[k];
      r += (kku < mu || (kku == mu && kki < mi)) ? 1 : 0;
    }
    if (r < KSEL){
      int lab = y_train[mi];
      atomicAdd(&votes[lab], w_train[mi]);
    }
  }
  __syncthreads();

  float bv = -1.f; int bl = 0;
  for (int l = t; l < NLAB; l += 256){
    float v = votes[l];
    if (v > bv){ bv = v; bl = l; }
  }
  rv[t] = bv; rl[t] = bl;
  __syncthreads();
  for (int s = 128; s > 0; s >>= 1){
    if (t < s){
      if (rv[t+s] > rv[t] || (rv[t+s] == rv[t] && rl[t+s] < rl[t])){
        rv[t] = rv[t+s]; rl[t] = rl[t+s];
      }
    }
    __syncthreads();
  }
  if (t == 0) out[m] = rl[0];
}

extern "C" void kernel_launch(void* const* d_in, const int* in_sizes, int n_in,
                              void* d_out, int out_size, void* d_ws, size_t ws_size,
                              hipStream_t stream)
{
  (void)in_sizes; (void)n_in; (void)out_size;
  const float* x_train = (const float*)d_in[0];
  const int*   y_train = (const int*)  d_in[1];
  const float* x_test  = (const float*)d_in[2];
  const float* w_train = (const float*)d_in[3];
  int* out = (int*)d_out;

  const size_t need = ((size_t)NTRAIN*DIM + NTRAIN + NTEST + NTEST
                       + (size_t)NTEST*CAP) * sizeof(float);
  if (ws_size >= need){
    float* xT = (float*)d_ws;
    float* b2 = xT + (size_t)NTRAIN*DIM;
    unsigned* Tu   = (unsigned*)(b2 + NTRAIN);
    unsigned* cnt  = Tu + NTEST;
    unsigned* cand = cnt + NTEST;
    prep<<<NTRAIN/256, 256, 0, stream>>>(x_train, xT, b2);
    pre_kernel<<<NTEST, 256, 0, stream>>>(xT, b2, x_test, Tu);
    hipMemsetAsync(cnt, 0, NTEST*sizeof(unsigned), stream);
    knnA<<<dim3(NTEST/TB, NCHUNK), 256, 0, stream>>>(xT, b2, x_test, Tu, cnt, cand);
    knnB<<<NTEST, 256, 0, stream>>>(x_train, xT, b2, x_test, y_train, w_train,
                                    cnt, cand, out);
  } else {
    knn_legacy<<<NTEST, 256, 0, stream>>>(x_train, x_test, y_train, w_train, out);
  }
}